// Round 16
// baseline (329.314 us; speedup 1.0000x reference)
//
#include <hip/hip_runtime.h>

typedef short short8 __attribute__((ext_vector_type(8)));
typedef short short4v __attribute__((ext_vector_type(4)));
typedef float f32x4 __attribute__((ext_vector_type(4)));
typedef unsigned short u16;

__device__ __forceinline__ u16 f2bf(float f) {
  unsigned int u = __builtin_bit_cast(unsigned int, f);
  u = (u + 0x7FFFu + ((u >> 16) & 1u)) >> 16;
  return (u16)u;
}
__device__ __forceinline__ short8 cvt8(float4 a, float4 b) {
  short8 v;
  v[0] = (short)f2bf(a.x); v[1] = (short)f2bf(a.y);
  v[2] = (short)f2bf(a.z); v[3] = (short)f2bf(a.w);
  v[4] = (short)f2bf(b.x); v[5] = (short)f2bf(b.y);
  v[6] = (short)f2bf(b.z); v[7] = (short)f2bf(b.w);
  return v;
}
__device__ __forceinline__ short8 cvt8s(float4 a, float4 b, float s) {
  short8 v;
  v[0] = (short)f2bf(a.x * s); v[1] = (short)f2bf(a.y * s);
  v[2] = (short)f2bf(a.z * s); v[3] = (short)f2bf(a.w * s);
  v[4] = (short)f2bf(b.x * s); v[5] = (short)f2bf(b.y * s);
  v[6] = (short)f2bf(b.z * s); v[7] = (short)f2bf(b.w * s);
  return v;
}

#define NPX 147456   // 64*48*48
#define L2E 1.44269504088896f

// ---------------------------------------------------------------------------
// Fused scan (R15 structure; x read as fp32 DIRECTLY -- no xcvt kernel, no
// xbf buffer). 256 blocks x 576 threads = 3 chains x 3 hd-waves per block
// (9 waves/CU). Chain = 16 seqs of one direction; wave owns hd slice
// [16wv,16wv+16) = gate tiles {q*48+16wv}. Per step: 24 x-MFMA (Wih q0,q1
// frags in regs, q2,q3 from one block-shared swizzled LDS copy) + 8 h-MFMA
// (Whh in regs, bias folded into K-channel 48; h-strip ch48 = 1.0). x frags
// loaded fp32 (L3-resident across 4 dirs) and converted in-register at
// refill; fp32 temps are transient (persistent footprint unchanged vs R15).
// comb store issued after the barrier (R15). exp2-native activations.
// ---------------------------------------------------------------------------
__global__ __launch_bounds__(576)
void fused_scan_kernel(const float* __restrict__ x,
    const float* __restrict__ wi0, const float* __restrict__ wi1,
    const float* __restrict__ wi2, const float* __restrict__ wi3,
    const float* __restrict__ u0, const float* __restrict__ u1,
    const float* __restrict__ u2, const float* __restrict__ u3,
    const float* __restrict__ bi0, const float* __restrict__ bh0,
    const float* __restrict__ bi1, const float* __restrict__ bh1,
    const float* __restrict__ bi2, const float* __restrict__ bh2,
    const float* __restrict__ bi3, const float* __restrict__ bh3,
    u16* __restrict__ comb)
{
  __shared__ u16 wl[36864];            // Wih [192 n][192 k] bf16, swizzled (73.7 KB)
  __shared__ u16 hs[3][2][1152];       // per-chain h dbuf [16 seq][72] (13.8 KB)

  const int tid   = threadIdx.x;
  const int chain = tid / 192;         // 0..2
  const int ctid  = tid - chain * 192;
  const int lane  = ctid & 63;
  const int wv    = ctid >> 6;         // 0..2 -> hd slice
  const int cl    = lane & 15;
  const int kg    = lane >> 4;
  const int dir   = blockIdx.x >> 6;   // 64 blocks per dir
  const int W     = blockIdx.x * 3 + chain;
  const int g     = W - dir * 192;
  const int bb    = g / 3;
  const int rc    = (g - bb * 3) * 16 + cl;
  const bool vert = dir < 2;
  const bool bwd  = (dir & 1) != 0;

  const float* wp  = dir == 0 ? wi0 : dir == 1 ? wi1 : dir == 2 ? wi2 : wi3;
  const float* up  = dir == 0 ? u0  : dir == 1 ? u1  : dir == 2 ? u2  : u3;
  const float* bip = dir == 0 ? bi0 : dir == 1 ? bi1 : dir == 2 ? bi2 : bi3;
  const float* bhp = dir == 0 ? bh0 : dir == 1 ? bh1 : dir == 2 ? bh2 : bh3;

  // ---- stage Wih -> LDS (one copy per block), log2e-scaled (gate g x2)
  for (int i = 0; i < 8; ++i) {
    int ch  = tid + 576 * i;           // 0..4607
    int row = ch / 24;
    int k0  = (ch % 24) * 8;
    float sc = (row >= 96 && row < 144) ? 2.0f * L2E : L2E;
    const float4* p = (const float4*)(wp + row * 192 + k0);
    *(short8*)&wl[(row * 192 + k0) ^ ((row & 7) << 3)] = cvt8s(p[0], p[1], sc);
  }

  // ---- chain geometry + first x frags (fp32 load + convert, issued early)
  const int tp0 = bwd ? 47 : 0;
  const int dpx = (vert ? 48 : 1) * (bwd ? -1 : 1);
  const int px0 = vert ? (bb * 48 + tp0) * 48 + rc : (bb * 48 + rc) * 48 + tp0;

  const float* xp = x + (size_t)px0 * 192 + kg * 8;
  const ptrdiff_t xstep = (ptrdiff_t)dpx * 192;
  short8 xf[6];
  {
    float4 ta[6], tb[6];
    #pragma unroll
    for (int kk = 0; kk < 6; ++kk) {
      const float4* p = (const float4*)(xp + kk * 32);
      ta[kk] = p[0]; tb[kk] = p[1];
    }
    #pragma unroll
    for (int kk = 0; kk < 6; ++kk) xf[kk] = cvt8(ta[kk], tb[kk]);
  }

  // ---- Wih gate tiles q=0,1 in registers (rows < 96 -> scale L2E)
  short8 wfr[2][6];
  #pragma unroll
  for (int q = 0; q < 2; ++q) {
    int n = q * 48 + wv * 16 + cl;
    #pragma unroll
    for (int kk = 0; kk < 6; ++kk) {
      const float4* p = (const float4*)(wp + n * 192 + kk * 32 + kg * 8);
      wfr[q][kk] = cvt8s(p[0], p[1], L2E);
    }
  }
  // ---- Whh frags (K padded 48->64), bias in K-channel 48
  short8 uf[4][2];
  #pragma unroll
  for (int q = 0; q < 4; ++q) {
    const float sc = (q == 2) ? 2.0f * L2E : L2E;
    int n = q * 48 + wv * 16 + cl;
    {
      const float4* p = (const float4*)(up + n * 48 + kg * 8);
      uf[q][0] = cvt8s(p[0], p[1], sc);
    }
    if (kg < 2) {
      const float4* p = (const float4*)(up + n * 48 + 32 + kg * 8);
      uf[q][1] = cvt8s(p[0], p[1], sc);
    } else if (kg == 2) {
      short8 v = {};                   // k=48 -> bias*sc
      v[0] = (short)f2bf((bip[n] + bhp[n]) * sc);
      uf[q][1] = v;
    } else {
      short8 z = {}; uf[q][1] = z;
    }
  }

  // ---- init this chain's h strips: zeros, ch48 = 1.0 (bias multiplier)
  for (int i = ctid; i < 2304; i += 192)
    (&hs[chain][0][0])[i] = (i % 72 == 48) ? (u16)0x3F80 : (u16)0;
  __syncthreads();

  f32x4 c = {0.f, 0.f, 0.f, 0.f};
  int hcur = 0;
  u16* cbp = comb + ((size_t)dir * NPX + px0) * 48 + wv * 16 + kg * 4;
  const ptrdiff_t cstep = (ptrdiff_t)dpx * 48;
  const int swz = (cl & 7) << 3;
  const int r2 = (96 + wv * 16 + cl) * 192 + kg * 8;
  const int r3 = (144 + wv * 16 + cl) * 192 + kg * 8;

  for (int t = 0; t < 48; ++t) {
    // h of previous step (issue early)
    short8 hb0 = *(const short8*)&hs[chain][hcur][cl * 72 + kg * 8];
    short8 hb1 = *(const short8*)&hs[chain][hcur][cl * 72 + 32 + kg * 8];

    f32x4 acc[4];
    #pragma unroll
    for (int q = 0; q < 4; ++q) acc[q] = (f32x4){0.f, 0.f, 0.f, 0.f};

    // x-phase: q0,q1 from regs; q2,q3 from shared LDS
    #pragma unroll
    for (int kk = 0; kk < 6; ++kk) {
      acc[0] = __builtin_amdgcn_mfma_f32_16x16x32_bf16(wfr[0][kk], xf[kk], acc[0], 0, 0, 0);
      acc[1] = __builtin_amdgcn_mfma_f32_16x16x32_bf16(wfr[1][kk], xf[kk], acc[1], 0, 0, 0);
      short8 w2 = *(const short8*)&wl[(r2 + kk * 32) ^ swz];
      short8 w3 = *(const short8*)&wl[(r3 + kk * 32) ^ swz];
      acc[2] = __builtin_amdgcn_mfma_f32_16x16x32_bf16(w2, xf[kk], acc[2], 0, 0, 0);
      acc[3] = __builtin_amdgcn_mfma_f32_16x16x32_bf16(w3, xf[kk], acc[3], 0, 0, 0);
    }

    // refill xf for t+1: fp32 loads + in-register convert (temps transient;
    // loads land during h-phase/epilogue, convert fills idle issue slots)
    if (t < 47) {
      xp += xstep;
      float4 ta[6], tb[6];
      #pragma unroll
      for (int kk = 0; kk < 6; ++kk) {
        const float4* p = (const float4*)(xp + kk * 32);
        ta[kk] = p[0]; tb[kk] = p[1];
      }
      #pragma unroll
      for (int kk = 0; kk < 6; ++kk) xf[kk] = cvt8(ta[kk], tb[kk]);
    }

    // h-phase (+bias via channel 48)
    #pragma unroll
    for (int q = 0; q < 4; ++q)
      acc[q] = __builtin_amdgcn_mfma_f32_16x16x32_bf16(uf[q][0], hb0, acc[q], 0, 0, 0);
    #pragma unroll
    for (int q = 0; q < 4; ++q)
      acc[q] = __builtin_amdgcn_mfma_f32_16x16x32_bf16(uf[q][1], hb1, acc[q], 0, 0, 0);

    // epilogue: lane -> seq=cl, hd = wv*16 + kg*4 + r
    short4v h4;
    #pragma unroll
    for (int r = 0; r < 4; ++r) {
      float ii = __builtin_amdgcn_rcpf(1.0f + __builtin_exp2f(-acc[0][r]));
      float ff = __builtin_amdgcn_rcpf(1.0f + __builtin_exp2f(-acc[1][r]));
      float gg = 1.0f - 2.0f * __builtin_amdgcn_rcpf(1.0f + __builtin_exp2f(acc[2][r]));
      float oo = __builtin_amdgcn_rcpf(1.0f + __builtin_exp2f(-acc[3][r]));
      float cc = ff * c[r] + ii * gg;
      c[r] = cc;
      float th = 1.0f - 2.0f * __builtin_amdgcn_rcpf(1.0f + __builtin_exp2f(cc * (2.0f * L2E)));
      h4[r] = (short)f2bf(oo * th);
    }
    *(short4v*)&hs[chain][hcur ^ 1][cl * 72 + wv * 16 + kg * 4] = h4;
    __syncthreads();
    // comb store AFTER the barrier: full-step runway before the next drain
    *(short4v*)cbp = h4;
    cbp += cstep;
    hcur ^= 1;
  }
}

// ---------------------------------------------------------------------------
// K3: out[px][c] = comb4[px][:] @ proj_w[c][:] + proj_b[c], fp32. (unchanged)
// ---------------------------------------------------------------------------
__global__ __launch_bounds__(256)
void proj_kernel(const u16* __restrict__ comb,
                 const float* __restrict__ pw,
                 const float* __restrict__ pb,
                 float* __restrict__ out)
{
  __shared__ u16 al[12288];
  const int tid  = threadIdx.x;
  const int lane = tid & 63;
  const int wv   = tid >> 6;
  const int cl   = lane & 15;
  const int kg   = lane >> 4;
  const int pxb  = blockIdx.x * 64;

  #pragma unroll
  for (int i = 0; i < 6; ++i) {
    int ch = tid + 256 * i;
    int pxl = ch / 24;
    int kk0 = (ch % 24) << 3;
    int d   = kk0 / 48;
    short8 v = *(const short8*)(comb + ((size_t)d * NPX + pxb + pxl) * 48 + (kk0 - d * 48));
    *(short8*)&al[(pxl * 192 + kk0) ^ ((pxl & 7) << 3)] = v;
  }

  short8 wf[3][6];
  #pragma unroll
  for (int nt = 0; nt < 3; ++nt) {
    int n = wv * 48 + nt * 16 + cl;
    #pragma unroll
    for (int kk = 0; kk < 6; ++kk) {
      const float4* p = (const float4*)(pw + n * 192 + kk * 32 + kg * 8);
      wf[nt][kk] = cvt8(p[0], p[1]);
    }
  }
  f32x4 bvv[3];
  #pragma unroll
  for (int nt = 0; nt < 3; ++nt)
    #pragma unroll
    for (int r = 0; r < 4; ++r)
      bvv[nt][r] = pb[wv * 48 + nt * 16 + kg * 4 + r];

  __syncthreads();

  f32x4 acc[3][4];
  #pragma unroll
  for (int nt = 0; nt < 3; ++nt)
    #pragma unroll
    for (int mi = 0; mi < 4; ++mi) acc[nt][mi] = bvv[nt];

  #pragma unroll
  for (int kk = 0; kk < 6; ++kk) {
    short8 bfr[4];
    #pragma unroll
    for (int mi = 0; mi < 4; ++mi) {
      int row = mi * 16 + cl;
      bfr[mi] = *(const short8*)&al[(row * 192 + kk * 32 + kg * 8) ^ ((row & 7) << 3)];
    }
    #pragma unroll
    for (int nt = 0; nt < 3; ++nt)
      #pragma unroll
      for (int mi = 0; mi < 4; ++mi)
        acc[nt][mi] = __builtin_amdgcn_mfma_f32_16x16x32_bf16(wf[nt][kk], bfr[mi], acc[nt][mi], 0, 0, 0);
  }

  #pragma unroll
  for (int nt = 0; nt < 3; ++nt)
    #pragma unroll
    for (int mi = 0; mi < 4; ++mi) {
      size_t o = (size_t)(pxb + mi * 16 + cl) * 192 + wv * 48 + nt * 16 + kg * 4;
      *(f32x4*)(out + o) = acc[nt][mi];
    }
}

extern "C" void kernel_launch(void* const* d_in, const int* in_sizes, int n_in,
                              void* d_out, int out_size, void* d_ws, size_t ws_size,
                              hipStream_t stream) {
  const float* x = (const float*)d_in[0];
  u16* comb = (u16*)d_ws;                              // 56.6 MB

  fused_scan_kernel<<<256, 576, 0, stream>>>(
      x,
      (const float*)d_in[1], (const float*)d_in[5],
      (const float*)d_in[9], (const float*)d_in[13],
      (const float*)d_in[2], (const float*)d_in[6],
      (const float*)d_in[10], (const float*)d_in[14],
      (const float*)d_in[3],  (const float*)d_in[4],
      (const float*)d_in[7],  (const float*)d_in[8],
      (const float*)d_in[11], (const float*)d_in[12],
      (const float*)d_in[15], (const float*)d_in[16],
      comb);

  proj_kernel<<<2304, 256, 0, stream>>>(
      comb, (const float*)d_in[17], (const float*)d_in[18], (float*)d_out);
}

// Round 17
// 209.721 us; speedup vs baseline: 1.5702x; 1.5702x over previous
//
#include <hip/hip_runtime.h>

typedef short short8 __attribute__((ext_vector_type(8)));
typedef short short4v __attribute__((ext_vector_type(4)));
typedef float f32x4 __attribute__((ext_vector_type(4)));
typedef unsigned short u16;

__device__ __forceinline__ u16 f2bf(float f) {
  unsigned int u = __builtin_bit_cast(unsigned int, f);
  u = (u + 0x7FFFu + ((u >> 16) & 1u)) >> 16;
  return (u16)u;
}
__device__ __forceinline__ short8 cvt8(float4 a, float4 b) {
  short8 v;
  v[0] = (short)f2bf(a.x); v[1] = (short)f2bf(a.y);
  v[2] = (short)f2bf(a.z); v[3] = (short)f2bf(a.w);
  v[4] = (short)f2bf(b.x); v[5] = (short)f2bf(b.y);
  v[6] = (short)f2bf(b.z); v[7] = (short)f2bf(b.w);
  return v;
}
__device__ __forceinline__ short8 cvt8s(float4 a, float4 b, float s) {
  short8 v;
  v[0] = (short)f2bf(a.x * s); v[1] = (short)f2bf(a.y * s);
  v[2] = (short)f2bf(a.z * s); v[3] = (short)f2bf(a.w * s);
  v[4] = (short)f2bf(b.x * s); v[5] = (short)f2bf(b.y * s);
  v[6] = (short)f2bf(b.z * s); v[7] = (short)f2bf(b.w * s);
  return v;
}

#define NPX 147456   // 64*48*48
#define L2E 1.44269504088896f

// ---------------------------------------------------------------------------
// K0: x fp32 -> xbf bf16, plain row-major. (Memory-floor ~28 us; buys the
// scan a halved fetch stream -- R16 proved removing it costs 2x.)
// ---------------------------------------------------------------------------
__global__ __launch_bounds__(256)
void xcvt_kernel(const float* __restrict__ x, u16* __restrict__ xbf)
{
  size_t c = ((size_t)blockIdx.x * 256 + threadIdx.x) * 8;
  const float4* p = (const float4*)(x + c);
  *(short8*)(xbf + c) = cvt8(p[0], p[1]);
}

// ---------------------------------------------------------------------------
// Fused scan (R10 structure + comb-store hoisted past the barrier = R15,
// the verified best). 256 blocks x 576 threads = 3 chains x 3 hd-waves per
// block (9 waves/CU). Chain = 16 seqs of one direction; wave owns hd slice
// [16wv,16wv+16) = gate tiles {q*48+16wv}. Per step: 24 x-MFMA (Wih q0,q1
// frags in regs, q2,q3 from one block-shared swizzled LDS copy) + 8 h-MFMA
// (Whh in regs, bias folded into K-channel 48; h-strip ch48 = 1.0). x
// streamed per-wave with refill-after-use. __syncthreads per step; the comb
// store is issued AFTER the barrier so its L2-completion latency has a full
// step of runway before the next barrier's vmcnt drain.
// ---------------------------------------------------------------------------
__global__ __launch_bounds__(576)
void fused_scan_kernel(const u16* __restrict__ xbf,
    const float* __restrict__ wi0, const float* __restrict__ wi1,
    const float* __restrict__ wi2, const float* __restrict__ wi3,
    const float* __restrict__ u0, const float* __restrict__ u1,
    const float* __restrict__ u2, const float* __restrict__ u3,
    const float* __restrict__ bi0, const float* __restrict__ bh0,
    const float* __restrict__ bi1, const float* __restrict__ bh1,
    const float* __restrict__ bi2, const float* __restrict__ bh2,
    const float* __restrict__ bi3, const float* __restrict__ bh3,
    u16* __restrict__ comb)
{
  __shared__ u16 wl[36864];            // Wih [192 n][192 k] bf16, swizzled (73.7 KB)
  __shared__ u16 hs[3][2][1152];       // per-chain h dbuf [16 seq][72] (13.8 KB)

  const int tid   = threadIdx.x;
  const int chain = tid / 192;         // 0..2
  const int ctid  = tid - chain * 192;
  const int lane  = ctid & 63;
  const int wv    = ctid >> 6;         // 0..2 -> hd slice
  const int cl    = lane & 15;
  const int kg    = lane >> 4;
  const int dir   = blockIdx.x >> 6;   // 64 blocks per dir
  const int W     = blockIdx.x * 3 + chain;
  const int g     = W - dir * 192;
  const int bb    = g / 3;
  const int rc    = (g - bb * 3) * 16 + cl;
  const bool vert = dir < 2;
  const bool bwd  = (dir & 1) != 0;

  const float* wp  = dir == 0 ? wi0 : dir == 1 ? wi1 : dir == 2 ? wi2 : wi3;
  const float* up  = dir == 0 ? u0  : dir == 1 ? u1  : dir == 2 ? u2  : u3;
  const float* bip = dir == 0 ? bi0 : dir == 1 ? bi1 : dir == 2 ? bi2 : bi3;
  const float* bhp = dir == 0 ? bh0 : dir == 1 ? bh1 : dir == 2 ? bh2 : bh3;

  // ---- stage Wih -> LDS (one copy per block), log2e-scaled (gate g x2)
  for (int i = 0; i < 8; ++i) {
    int ch  = tid + 576 * i;           // 0..4607
    int row = ch / 24;
    int k0  = (ch % 24) * 8;
    float sc = (row >= 96 && row < 144) ? 2.0f * L2E : L2E;
    const float4* p = (const float4*)(wp + row * 192 + k0);
    *(short8*)&wl[(row * 192 + k0) ^ ((row & 7) << 3)] = cvt8s(p[0], p[1], sc);
  }

  // ---- chain geometry + first x frags (issued early)
  const int tp0 = bwd ? 47 : 0;
  const int dpx = (vert ? 48 : 1) * (bwd ? -1 : 1);
  const int px0 = vert ? (bb * 48 + tp0) * 48 + rc : (bb * 48 + rc) * 48 + tp0;

  const u16* xp = xbf + (size_t)px0 * 192 + kg * 8;
  const ptrdiff_t xstep = (ptrdiff_t)dpx * 192;
  short8 xf[6];
  #pragma unroll
  for (int kk = 0; kk < 6; ++kk) xf[kk] = *(const short8*)(xp + kk * 32);

  // ---- Wih gate tiles q=0,1 in registers (rows < 96 -> scale L2E)
  short8 wfr[2][6];
  #pragma unroll
  for (int q = 0; q < 2; ++q) {
    int n = q * 48 + wv * 16 + cl;
    #pragma unroll
    for (int kk = 0; kk < 6; ++kk) {
      const float4* p = (const float4*)(wp + n * 192 + kk * 32 + kg * 8);
      wfr[q][kk] = cvt8s(p[0], p[1], L2E);
    }
  }
  // ---- Whh frags (K padded 48->64), bias in K-channel 48
  short8 uf[4][2];
  #pragma unroll
  for (int q = 0; q < 4; ++q) {
    const float sc = (q == 2) ? 2.0f * L2E : L2E;
    int n = q * 48 + wv * 16 + cl;
    {
      const float4* p = (const float4*)(up + n * 48 + kg * 8);
      uf[q][0] = cvt8s(p[0], p[1], sc);
    }
    if (kg < 2) {
      const float4* p = (const float4*)(up + n * 48 + 32 + kg * 8);
      uf[q][1] = cvt8s(p[0], p[1], sc);
    } else if (kg == 2) {
      short8 v = {};                   // k=48 -> bias*sc
      v[0] = (short)f2bf((bip[n] + bhp[n]) * sc);
      uf[q][1] = v;
    } else {
      short8 z = {}; uf[q][1] = z;
    }
  }

  // ---- init this chain's h strips: zeros, ch48 = 1.0 (bias multiplier)
  for (int i = ctid; i < 2304; i += 192)
    (&hs[chain][0][0])[i] = (i % 72 == 48) ? (u16)0x3F80 : (u16)0;
  __syncthreads();

  f32x4 c = {0.f, 0.f, 0.f, 0.f};
  int hcur = 0;
  u16* cbp = comb + ((size_t)dir * NPX + px0) * 48 + wv * 16 + kg * 4;
  const ptrdiff_t cstep = (ptrdiff_t)dpx * 48;
  const int swz = (cl & 7) << 3;
  const int r2 = (96 + wv * 16 + cl) * 192 + kg * 8;
  const int r3 = (144 + wv * 16 + cl) * 192 + kg * 8;

  for (int t = 0; t < 48; ++t) {
    // h of previous step (issue early)
    short8 hb0 = *(const short8*)&hs[chain][hcur][cl * 72 + kg * 8];
    short8 hb1 = *(const short8*)&hs[chain][hcur][cl * 72 + 32 + kg * 8];

    f32x4 acc[4];
    #pragma unroll
    for (int q = 0; q < 4; ++q) acc[q] = (f32x4){0.f, 0.f, 0.f, 0.f};

    // x-phase: q0,q1 from regs; q2,q3 from shared LDS
    #pragma unroll
    for (int kk = 0; kk < 6; ++kk) {
      acc[0] = __builtin_amdgcn_mfma_f32_16x16x32_bf16(wfr[0][kk], xf[kk], acc[0], 0, 0, 0);
      acc[1] = __builtin_amdgcn_mfma_f32_16x16x32_bf16(wfr[1][kk], xf[kk], acc[1], 0, 0, 0);
      short8 w2 = *(const short8*)&wl[(r2 + kk * 32) ^ swz];
      short8 w3 = *(const short8*)&wl[(r3 + kk * 32) ^ swz];
      acc[2] = __builtin_amdgcn_mfma_f32_16x16x32_bf16(w2, xf[kk], acc[2], 0, 0, 0);
      acc[3] = __builtin_amdgcn_mfma_f32_16x16x32_bf16(w3, xf[kk], acc[3], 0, 0, 0);
    }

    // refill xf for t+1 (issues after x-MFMAs; lands during h-phase/epilogue)
    if (t < 47) {
      xp += xstep;
      #pragma unroll
      for (int kk = 0; kk < 6; ++kk) xf[kk] = *(const short8*)(xp + kk * 32);
    }

    // h-phase (+bias via channel 48)
    #pragma unroll
    for (int q = 0; q < 4; ++q)
      acc[q] = __builtin_amdgcn_mfma_f32_16x16x32_bf16(uf[q][0], hb0, acc[q], 0, 0, 0);
    #pragma unroll
    for (int q = 0; q < 4; ++q)
      acc[q] = __builtin_amdgcn_mfma_f32_16x16x32_bf16(uf[q][1], hb1, acc[q], 0, 0, 0);

    // epilogue: lane -> seq=cl, hd = wv*16 + kg*4 + r
    short4v h4;
    #pragma unroll
    for (int r = 0; r < 4; ++r) {
      float ii = __builtin_amdgcn_rcpf(1.0f + __builtin_exp2f(-acc[0][r]));
      float ff = __builtin_amdgcn_rcpf(1.0f + __builtin_exp2f(-acc[1][r]));
      float gg = 1.0f - 2.0f * __builtin_amdgcn_rcpf(1.0f + __builtin_exp2f(acc[2][r]));
      float oo = __builtin_amdgcn_rcpf(1.0f + __builtin_exp2f(-acc[3][r]));
      float cc = ff * c[r] + ii * gg;
      c[r] = cc;
      float th = 1.0f - 2.0f * __builtin_amdgcn_rcpf(1.0f + __builtin_exp2f(cc * (2.0f * L2E)));
      h4[r] = (short)f2bf(oo * th);
    }
    *(short4v*)&hs[chain][hcur ^ 1][cl * 72 + wv * 16 + kg * 4] = h4;
    __syncthreads();
    // comb store AFTER the barrier: full-step runway before the next drain
    *(short4v*)cbp = h4;
    cbp += cstep;
    hcur ^= 1;
  }
}

// ---------------------------------------------------------------------------
// K3: out[px][c] = comb4[px][:] @ proj_w[c][:] + proj_b[c], fp32.
// ---------------------------------------------------------------------------
__global__ __launch_bounds__(256)
void proj_kernel(const u16* __restrict__ comb,
                 const float* __restrict__ pw,
                 const float* __restrict__ pb,
                 float* __restrict__ out)
{
  __shared__ u16 al[12288];
  const int tid  = threadIdx.x;
  const int lane = tid & 63;
  const int wv   = tid >> 6;
  const int cl   = lane & 15;
  const int kg   = lane >> 4;
  const int pxb  = blockIdx.x * 64;

  #pragma unroll
  for (int i = 0; i < 6; ++i) {
    int ch = tid + 256 * i;
    int pxl = ch / 24;
    int kk0 = (ch % 24) << 3;
    int d   = kk0 / 48;
    short8 v = *(const short8*)(comb + ((size_t)d * NPX + pxb + pxl) * 48 + (kk0 - d * 48));
    *(short8*)&al[(pxl * 192 + kk0) ^ ((pxl & 7) << 3)] = v;
  }

  short8 wf[3][6];
  #pragma unroll
  for (int nt = 0; nt < 3; ++nt) {
    int n = wv * 48 + nt * 16 + cl;
    #pragma unroll
    for (int kk = 0; kk < 6; ++kk) {
      const float4* p = (const float4*)(pw + n * 192 + kk * 32 + kg * 8);
      wf[nt][kk] = cvt8(p[0], p[1]);
    }
  }
  f32x4 bvv[3];
  #pragma unroll
  for (int nt = 0; nt < 3; ++nt)
    #pragma unroll
    for (int r = 0; r < 4; ++r)
      bvv[nt][r] = pb[wv * 48 + nt * 16 + kg * 4 + r];

  __syncthreads();

  f32x4 acc[3][4];
  #pragma unroll
  for (int nt = 0; nt < 3; ++nt)
    #pragma unroll
    for (int mi = 0; mi < 4; ++mi) acc[nt][mi] = bvv[nt];

  #pragma unroll
  for (int kk = 0; kk < 6; ++kk) {
    short8 bfr[4];
    #pragma unroll
    for (int mi = 0; mi < 4; ++mi) {
      int row = mi * 16 + cl;
      bfr[mi] = *(const short8*)&al[(row * 192 + kk * 32 + kg * 8) ^ ((row & 7) << 3)];
    }
    #pragma unroll
    for (int nt = 0; nt < 3; ++nt)
      #pragma unroll
      for (int mi = 0; mi < 4; ++mi)
        acc[nt][mi] = __builtin_amdgcn_mfma_f32_16x16x32_bf16(wf[nt][kk], bfr[mi], acc[nt][mi], 0, 0, 0);
  }

  #pragma unroll
  for (int nt = 0; nt < 3; ++nt)
    #pragma unroll
    for (int mi = 0; mi < 4; ++mi) {
      size_t o = (size_t)(pxb + mi * 16 + cl) * 192 + wv * 48 + nt * 16 + kg * 4;
      *(f32x4*)(out + o) = acc[nt][mi];
    }
}

extern "C" void kernel_launch(void* const* d_in, const int* in_sizes, int n_in,
                              void* d_out, int out_size, void* d_ws, size_t ws_size,
                              hipStream_t stream) {
  const float* x = (const float*)d_in[0];
  u16* xbf  = (u16*)d_ws;                              // 56.6 MB row-major bf16 x
  u16* comb = (u16*)d_ws + (size_t)NPX * 192;          // 56.6 MB

  xcvt_kernel<<<13824, 256, 0, stream>>>(x, xbf);

  fused_scan_kernel<<<256, 576, 0, stream>>>(
      xbf,
      (const float*)d_in[1], (const float*)d_in[5],
      (const float*)d_in[9], (const float*)d_in[13],
      (const float*)d_in[2], (const float*)d_in[6],
      (const float*)d_in[10], (const float*)d_in[14],
      (const float*)d_in[3],  (const float*)d_in[4],
      (const float*)d_in[7],  (const float*)d_in[8],
      (const float*)d_in[11], (const float*)d_in[12],
      (const float*)d_in[15], (const float*)d_in[16],
      comb);

  proj_kernel<<<2304, 256, 0, stream>>>(
      comb, (const float*)d_in[17], (const float*)d_in[18], (float*)d_out);
}